// Round 11
// baseline (238.824 us; speedup 1.0000x reference)
//
#include <hip/hip_runtime.h>

// Pre-emphasis IIR: out[t] = y[t] + 0.85*out[t-1], shift SKIP=91, scale 32768,
// clip, astype(int16) (trunc toward zero); harness reads d_out as int32.
//
// R15 -> R16: R15 proved guaranteed 9-deep LDS-DMA bursts don't move the
// 2.5 TB/s plateau. Residency math: wave lifetime ~12.6us with <=10% of it
// holding outstanding loads -> the invariant across ALL ~80us variants is
// ONE-SHOT waves (single load phase, then exit). Duty cycle, not depth.
// R16 = persistent waves + double-buffered LDS-DMA pipeline: 512 blocks x
// 4 waves (2 blk/CU, ALL resident), each wave owns 8 consecutive tiles;
// per tile issue next tile's 8 global_load_lds into the other buffer, then
// COUNTED vmcnt(16) (next-tile loads + prev-tile stores stay in flight,
// queue never drains mid-chain), ds_read, R15-verified scan, stores. Carry
// crosses tiles in a register (warm window of tile t == last window of
// tile t-1 -> tlast = t[7]; warm loads vanish after each wave's first tile).
// No dest registers anywhere in staging -> R14's RA hazard impossible.
// Boundary tiles use R15's verified guarded path.

#define BLOCK   256
#define SKIP    91
#define COEF    0.85f
#define CHUNK_N 256                   // 64 lanes x 4 floats
#define CHUNKS  8                     // output windows per tile
#define SEG     (CHUNKS * CHUNK_N)    // 2048 outputs per tile
#define WPB     (BLOCK / 64)          // 4 waves per block
#define TPW     8                     // tiles per wave (persistent chain)
#define NW      9                     // buffer capacity in windows (warm+8)
#define BUF_F   (NW * CHUNK_N)        // 2304 floats (9 KB) per buffer

typedef int v4i __attribute__((ext_vector_type(4)));
typedef __attribute__((address_space(3))) void       as3_void;
typedef const __attribute__((address_space(1))) void as1_void;

#define VMWAIT(N) asm volatile("s_waitcnt vmcnt(" #N ")" ::: "memory")

__device__ __forceinline__ int cvt16(float v) {
    float s = v * 32768.f;
    s = fminf(fmaxf(s, -32768.f), 32767.f);   // v_med3_f32
    return (int)s;                            // trunc toward zero
}

__device__ __forceinline__ float chain4(const float4& v) {
    float a1 = fmaf(v.x, COEF, v.y);
    float a2 = fmaf(a1, COEF, v.z);
    return fmaf(a2, COEF, v.w);
}

template <int N>
__device__ __forceinline__ void wscan_multi(float (&t)[N], int lane) {
    const float K1  = COEF * COEF * COEF * COEF;    // c^4
    const float K2  = K1 * K1, K4 = K2 * K2, K8 = K4 * K4, K16 = K8 * K8;
    const float KS[5] = {K1, K2, K4, K8, K16};      // c^128 step ~9e-10: dropped
#pragma unroll
    for (int d = 0; d < 5; ++d) {
        const int sh = 1 << d;
        float u[N];
#pragma unroll
        for (int c = 0; c < N; ++c) u[c] = __shfl_up(t[c], sh, 64);
#pragma unroll
        for (int c = 0; c < N; ++c)
            t[c] = (lane >= sh) ? fmaf(u[c], KS[d], t[c]) : t[c];
    }
}

// Emit one 256-output chunk. x = its window, t = window's scanned value,
// Tp = broadcast total of the PREVIOUS window, tsh = shfl_up(t,1).
__device__ __forceinline__ void emit_chunk(const float4& x, float tsh, float Tp,
                                           int lane, float wq,
                                           int* __restrict__ out, long ob) {
    const float C1 = COEF, C2 = COEF * COEF, C3 = C2 * COEF;
    float u = (lane == 0) ? 0.f : tsh;
    float p = fmaf(Tp, wq, u);            // full value at prev-lane elem3
    float s1 = fmaf(x.x, COEF, x.y);
    float s2 = fmaf(s1, COEF, x.z);
    v4i iv;                               // realigned by SKIP%4=3
    iv.x = cvt16(p);
    iv.y = cvt16(fmaf(p, C1, x.x));
    iv.z = cvt16(fmaf(p, C2, s1));
    iv.w = cvt16(fmaf(p, C3, s2));
    *reinterpret_cast<v4i*>(out + ob) = iv;
}

// First tile of a chain: buffer holds 9 windows (w=0 warm). Returns t[8].
__device__ __forceinline__ float compute9(const float* lb, int lane, float wq,
                                          int* __restrict__ out, long segBase) {
    const float* lr = lb + 4 * lane;
    float4 xw[9];
#pragma unroll
    for (int w = 0; w < 9; ++w)
        xw[w] = *reinterpret_cast<const float4*>(lr + w * CHUNK_N);
    float t[9];
#pragma unroll
    for (int w = 0; w < 9; ++w) t[w] = chain4(xw[w]);
    wscan_multi<9>(t, lane);
#pragma unroll
    for (int c = 0; c < 8; ++c)
        emit_chunk(xw[c + 1], __shfl_up(t[c + 1], 1, 64), __shfl(t[c], 63, 64),
                   lane, wq, out, segBase + c * CHUNK_N + 4 * (long)lane);
    return t[8];
}

// Steady tile: buffer holds 8 windows; carry = prev tile's t[last]. Ret t[7].
__device__ __forceinline__ float compute8(const float* lb, float tlast,
                                          int lane, float wq,
                                          int* __restrict__ out, long segBase) {
    const float* lr = lb + 4 * lane;
    float4 xw[8];
#pragma unroll
    for (int w = 0; w < 8; ++w)
        xw[w] = *reinterpret_cast<const float4*>(lr + w * CHUNK_N);
    float t[8];
#pragma unroll
    for (int w = 0; w < 8; ++w) t[w] = chain4(xw[w]);
    wscan_multi<8>(t, lane);
#pragma unroll
    for (int c = 0; c < 8; ++c) {
        float Tp = (c == 0) ? __shfl(tlast, 63, 64) : __shfl(t[c - 1], 63, 64);
        emit_chunk(xw[c], __shfl_up(t[c], 1, 64), Tp,
                   lane, wq, out, segBase + c * CHUNK_N + 4 * (long)lane);
    }
    return t[7];
}

// ---- guarded (edge) path: per-element bounds, verified in R13/R15 ----
__device__ __forceinline__ float4 ld_guard(const float* __restrict__ sig,
                                           long yb, long n) {
    float4 x;
    x.x = (yb + 0 >= 0 && yb + 0 < n) ? sig[yb + 0] : 0.f;
    x.y = (yb + 1 >= 0 && yb + 1 < n) ? sig[yb + 1] : 0.f;
    x.z = (yb + 2 >= 0 && yb + 2 < n) ? sig[yb + 2] : 0.f;
    x.w = (yb + 3 >= 0 && yb + 3 < n) ? sig[yb + 3] : 0.f;
    return x;
}

__device__ void run_guard(const float* __restrict__ sig, int* __restrict__ out,
                          long segBase, long ln, int lane, float wq) {
    const float C1 = COEF, C2 = COEF * COEF, C3 = C2 * COEF;
    float4 x[9];
#pragma unroll
    for (int c = 0; c < 8; ++c)
        x[c] = ld_guard(sig, segBase + (SKIP + 1) + (long)c * CHUNK_N
                             + 4 * (long)lane, ln);
    x[8] = ld_guard(sig, segBase - 164 + 4 * (long)lane, ln);
    float t[9];
#pragma unroll
    for (int c = 0; c < 9; ++c) t[c] = chain4(x[c]);
    wscan_multi<9>(t, lane);
    float tsh[8], Tp[8];
#pragma unroll
    for (int c = 0; c < 8; ++c) tsh[c] = __shfl_up(t[c], 1, 64);
#pragma unroll
    for (int c = 0; c < 8; ++c) Tp[c] = __shfl(t[c == 0 ? 8 : c - 1], 63, 64);
    const long oLim = ln - SKIP;
#pragma unroll
    for (int c = 0; c < 8; ++c) {
        float u  = (lane == 0) ? 0.f : tsh[c];
        float p  = fmaf(Tp[c], wq, u);
        float s1 = fmaf(x[c].x, COEF, x[c].y);
        float s2 = fmaf(s1, COEF, x[c].z);
        v4i iv;
        iv.x = cvt16(p);
        iv.y = cvt16(fmaf(p, C1, x[c].x));
        iv.z = cvt16(fmaf(p, C2, s1));
        iv.w = cvt16(fmaf(p, C3, s2));
        const long ob = segBase + (long)c * CHUNK_N + 4 * (long)lane;
        if (ob + 0 >= oLim) iv.x = 0;
        if (ob + 1 >= oLim) iv.y = 0;
        if (ob + 2 >= oLim) iv.z = 0;
        if (ob + 3 >= oLim) iv.w = 0;
        if (ob + 0 < ln) out[ob + 0] = iv.x;
        if (ob + 1 < ln) out[ob + 1] = iv.y;
        if (ob + 2 < ln) out[ob + 2] = iv.z;
        if (ob + 3 < ln) out[ob + 3] = iv.w;
    }
}

__device__ __forceinline__ bool fast_tile(long t, long ln) {
    long sb = t * SEG;
    return (sb >= 164) && (sb + SEG + SKIP + 1 <= ln);
}

__global__ __launch_bounds__(BLOCK, 2) void preemph_kernel(
        const float* __restrict__ sig, int* __restrict__ out, int n) {
    __shared__ float lds[WPB][2][BUF_F];    // 73728 B: wave-private dbl buffers
    const long ln   = n;
    const int  lane = threadIdx.x & 63;
    const int  wid  = threadIdx.x >> 6;
    const long ntiles = (ln + SEG - 1) / SEG;
    const long t0 = ((long)blockIdx.x * WPB + wid) * TPW;
    if (t0 >= ntiles) return;
    const long t1 = (t0 + TPW < ntiles) ? t0 + TPW : ntiles;

    // c^(4*lane): prev-lane carry weight (lane 0 -> 1.0)
    const float wq = exp2f((float)lane * (4.0f * -0.23446525109f)); // log2(0.85)

    // guarded tiles exist only at array extremes
    long cl = t0, cr = t1;
    while (cl < cr && !fast_tile(cl, ln)) { run_guard(sig, out, cl * SEG, ln, lane, wq); ++cl; }
    while (cr > cl && !fast_tile(cr - 1, ln)) --cr;

    if (cl < cr) {
        float* b0 = &lds[wid][0][0];
        float* b1 = &lds[wid][1][0];

        // prologue: stage chain-start tile with warm window (9 loads)
        const float* g9 = sig + cl * SEG - 164 + 4 * (long)lane;
#pragma unroll
        for (int w = 0; w < 9; ++w)
            __builtin_amdgcn_global_load_lds((as1_void*)(g9 + w * CHUNK_N),
                                             (as3_void*)(b0 + w * CHUNK_N),
                                             16, 0, 0);
        float tlast = 0.f;
        int par = 0;
        for (long t = cl; t < cr; ++t) {
            const bool first = (t == cl), hasN = (t + 1 < cr);
            if (hasN) {   // stage next tile into the other buffer (8 loads)
                const float* g8 = sig + (t + 1) * SEG + (SKIP + 1) + 4 * (long)lane;
                float* nb = par ? b0 : b1;
#pragma unroll
                for (int c = 0; c < 8; ++c)
                    __builtin_amdgcn_global_load_lds((as1_void*)(g8 + c * CHUNK_N),
                                                     (as3_void*)(nb + c * CHUNK_N),
                                                     16, 0, 0);
            }
            // counted wait: current tile's loads done; next-tile loads (8)
            // and prev-tile stores (8) REMAIN in flight -> continuous issue.
            if (first) { if (hasN) VMWAIT(8);  else VMWAIT(0); }
            else       { if (hasN) VMWAIT(16); else VMWAIT(8); }
            __builtin_amdgcn_sched_barrier(0);

            const float* cb = par ? b1 : b0;
            if (first) tlast = compute9(cb, lane, wq, out, t * SEG);
            else       tlast = compute8(cb, tlast, lane, wq, out, t * SEG);
            par ^= 1;
        }
    }
    for (long t = cr; t < t1; ++t) run_guard(sig, out, t * SEG, ln, lane, wq);
}

extern "C" void kernel_launch(void* const* d_in, const int* in_sizes, int n_in,
                              void* d_out, int out_size, void* d_ws, size_t ws_size,
                              hipStream_t stream) {
    const float* sig = (const float*)d_in[0];
    int* out = (int*)d_out;
    int n = in_sizes[0];
    long ntiles = ((long)n + SEG - 1) / SEG;
    int grid = (int)((ntiles + (long)WPB * TPW - 1) / ((long)WPB * TPW));
    preemph_kernel<<<grid, BLOCK, 0, stream>>>(sig, out, n);
}

// Round 12
// 231.974 us; speedup vs baseline: 1.0295x; 1.0295x over previous
//
#include <hip/hip_runtime.h>

// Pre-emphasis IIR: out[t] = y[t] + 0.85*out[t-1], shift SKIP=91, scale 32768,
// clip, astype(int16) (trunc toward zero); harness reads d_out as int32.
//
// R16 -> R17: RESTORE THE PROVEN BEST (R5, 79.4us kernel / 231.25us bench).
// Rounds 6-16 systematically falsified every candidate bottleneck on this
// ~80us plateau: per-wave MLP depth (R12 asm batch, R15 guaranteed LDS-DMA
// burst: null), dependence-chain latency (R13 parallel scan levels: null),
// NT vs plain stores (R10: identical), bank conflicts (scan variants: 0
// conflicts, same time), continuous pipelined issue with counted vmcnt
// (R16 persistent waves: REGRESSED to 103us). Across all passing variants
// duration is invariant at 79-84us while occupancy (30-71%), VALUBusy
// (7-22%), and DS usage (0-35%) vary 3x -- nothing saturated; wave lifetime
// and residency self-compensate (time = sum(lifetime)/slots ~ const). The
// combined 3.3 TB/s (134 MB read + 134 MB write / 80us) matches the
// read-side service rate implied by the m13 copy ceiling (6.29 TB/s total
// = ~3.15 TB/s each way). Conclusion: system service-rate floor for this
// R/W mix, not a kernel-structure problem. This file = R5 verbatim.

#define BLOCK   256
#define CH      16
#define TILE    (BLOCK * CH)        // 4096
#define SKIP    91
#define WARM    71                  // tStart = tileBase + 20 (16B-aligned)
#define COEF    0.85f
#define LOADN   (TILE + 72)         // 4168 floats staged
#define PAD4(p) ((p) + 4 * ((p) >> 5))   // 4-aligned p stays 16B-aligned
#define LDS_F   4688                // > PAD4(4167) = 4687; 18.75 KB -> 8 blk/CU

typedef int v4i __attribute__((ext_vector_type(4)));

__global__ __launch_bounds__(BLOCK) void preemph_kernel(
        const float* __restrict__ sig, int* __restrict__ out, int n) {
    __shared__ float lds[LDS_F];
    const int  tid      = threadIdx.x;
    const long tileBase = (long)blockIdx.x * TILE;
    const long tStart   = tileBase + (SKIP - WARM);   // tileBase + 20, 16B-aligned

    float4* const l4 = reinterpret_cast<float4*>(lds);

    // Phase 1: coalesced float4 global -> ds_write_b128 (padded).
    for (int base = 0; base < LOADN; base += BLOCK * 4) {
        int off = base + tid * 4;
        if (off < LOADN) {
            long t = tStart + off;
            float4 v;
            if (t + 3 < (long)n) {
                v = *reinterpret_cast<const float4*>(sig + t);
            } else {
                v.x = (t + 0 < (long)n) ? sig[t + 0] : 0.f;
                v.y = (t + 1 < (long)n) ? sig[t + 1] : 0.f;
                v.z = (t + 2 < (long)n) ? sig[t + 2] : 0.f;
                v.w = (t + 3 < (long)n) ? sig[t + 3] : 0.f;
            }
            l4[PAD4(off) >> 2] = v;
        }
    }
    __syncthreads();

    // Phase 2: fused scan + convert, 22 x ds_read_b128 per thread.
    // Thread t owns LDS floats [16t, 16t+88): 71 warm-up, 16 outputs, 1 spare.
    const int p0 = tid * CH;
    float acc = 0.f;
    int res[CH];
#pragma unroll
    for (int k = 0; k < 22; ++k) {
        float4 v = l4[PAD4(p0 + 4 * k) >> 2];
#pragma unroll
        for (int c = 0; c < 4; ++c) {
            const int e = 4 * k + c;              // compile-time
            float x = (c == 0) ? v.x : (c == 1) ? v.y : (c == 2) ? v.z : v.w;
            if (e < WARM) {
                acc = fmaf(acc, COEF, x);
            } else if (e < WARM + CH) {
                acc = fmaf(acc, COEF, x);
                float s = acc * 32768.f;
                s = fminf(fmaxf(s, -32768.f), 32767.f);
                res[e - WARM] = (int)s;           // trunc toward zero
            }
        }
    }
    // Tail: outputs >= n-SKIP are zero-padded.
    const long oBase = tileBase + p0;
    const long oLim  = (long)n - SKIP;
#pragma unroll
    for (int j = 0; j < CH; ++j)
        if (oBase + j >= oLim) res[j] = 0;
    __syncthreads();   // phase-2 reads (incl. neighbors' warm-up) must finish

    // Phase 3: int results -> LDS via 4 x ds_write_b128 (bit-cast, same layout).
#pragma unroll
    for (int k = 0; k < 4; ++k) {
        float4 v;
        v.x = __int_as_float(res[4 * k + 0]);
        v.y = __int_as_float(res[4 * k + 1]);
        v.z = __int_as_float(res[4 * k + 2]);
        v.w = __int_as_float(res[4 * k + 3]);
        l4[PAD4(p0 + 4 * k) >> 2] = v;
    }
    __syncthreads();

    // Phase 4: linear ds_read_b128 -> coalesced nontemporal int4 store.
    for (int base = 0; base < TILE; base += BLOCK * 4) {
        int off = base + tid * 4;                 // TILE = 4*1024: no predicate
        long o  = tileBase + off;
        float4 v = l4[PAD4(off) >> 2];
        v4i iv;
        iv.x = __float_as_int(v.x);
        iv.y = __float_as_int(v.y);
        iv.z = __float_as_int(v.z);
        iv.w = __float_as_int(v.w);
        if (o + 3 < (long)n) {
            __builtin_nontemporal_store(iv, reinterpret_cast<v4i*>(out + o));
        } else {
            if (o + 0 < (long)n) out[o + 0] = iv.x;
            if (o + 1 < (long)n) out[o + 1] = iv.y;
            if (o + 2 < (long)n) out[o + 2] = iv.z;
        }
    }
}

extern "C" void kernel_launch(void* const* d_in, const int* in_sizes, int n_in,
                              void* d_out, int out_size, void* d_ws, size_t ws_size,
                              hipStream_t stream) {
    const float* sig = (const float*)d_in[0];
    int* out = (int*)d_out;
    int n = in_sizes[0];
    int grid = (int)(((long)n + TILE - 1) / TILE);
    preemph_kernel<<<grid, BLOCK, 0, stream>>>(sig, out, n);
}